// Round 5
// baseline (271.851 us; speedup 1.0000x reference)
//
#include <hip/hip_runtime.h>
#include <stdint.h>

typedef unsigned short u16;
typedef __bf16 bf16x8 __attribute__((ext_vector_type(8)));
typedef float f32x4 __attribute__((ext_vector_type(4)));

#define SEQ    1024
#define DMODEL 1024
#define NB     4
#define NH     16
#define DH     64
#define QBLK   128
#define KVB    64
#define LOG2E  1.4426950408889634f

// ---------- bf16 helpers ----------
__device__ __forceinline__ u16 f2bf(float f) {
  uint32_t u = __builtin_bit_cast(uint32_t, f);
  u += 0x7fffu + ((u >> 16) & 1u);   // round-to-nearest-even
  return (u16)(u >> 16);
}
__device__ __forceinline__ float bf2f(u16 h) {
  uint32_t u = ((uint32_t)h) << 16;
  return __builtin_bit_cast(float, u);
}

#define MFMA16(a, b, c) __builtin_amdgcn_mfma_f32_16x16x32_bf16((a), (b), (c), 0, 0, 0)

// ---------- async global->LDS (16B) ----------
__device__ __forceinline__ void gload_lds16(const u16* g, uintptr_t lds_addr) {
  __builtin_amdgcn_global_load_lds(
      (__attribute__((address_space(1))) void*)(uintptr_t)g,
      (__attribute__((address_space(3))) void*)lds_addr,
      16, 0, 0);
}

// ---------------- split f32 -> (hi, lo) bf16, 8 elems / thread ----------------
__global__ void split_kernel(const float* __restrict__ src, u16* __restrict__ hi,
                             u16* __restrict__ lo, int n8) {
  int i = blockIdx.x * blockDim.x + threadIdx.x;
  if (i >= n8) return;
  float f[8];
  float4 v0 = *(const float4*)(src + (size_t)i * 8);
  float4 v1 = *(const float4*)(src + (size_t)i * 8 + 4);
  f[0] = v0.x; f[1] = v0.y; f[2] = v0.z; f[3] = v0.w;
  f[4] = v1.x; f[5] = v1.y; f[6] = v1.z; f[7] = v1.w;
  union { u16 u[8]; uint4 v; } H, L;
#pragma unroll
  for (int e = 0; e < 8; ++e) {
    u16 h = f2bf(f[e]);
    H.u[e] = h;
    L.u[e] = f2bf(f[e] - bf2f(h));
  }
  *(uint4*)(hi + (size_t)i * 8) = H.v;
  *(uint4*)(lo + (size_t)i * 8) = L.v;
}

// ---------------- RoPE on Q,K hi/lo pairs (in place) ----------------
__global__ void rope_kernel(u16* __restrict__ Qh, u16* __restrict__ Ql,
                            u16* __restrict__ Kh, u16* __restrict__ Kl) {
  const int nP = (NB * SEQ) * (DMODEL / 2);
  int idx = blockIdx.x * blockDim.x + threadIdx.x;
  u16 *bh, *bl; int p;
  if (idx < nP) { bh = Qh; bl = Ql; p = idx; }
  else          { bh = Kh; bl = Kl; p = idx - nP; }
  int row = p >> 9;           // 512 pairs per row
  int pi  = p & 511;
  int t   = row & (SEQ - 1);
  int fi  = pi & 31;
  float inv = exp2f((float)fi * (-13.287712379549449f / 32.0f)); // 10000^(-fi/32)
  float ang = (float)t * inv;
  float sn, cs;
  sincosf(ang, &sn, &cs);
  size_t off = (size_t)row * DMODEL + pi * 2;
  uint32_t vh = *(uint32_t*)(bh + off);
  uint32_t vl = *(uint32_t*)(bl + off);
  float e = bf2f((u16)(vh & 0xffffu)) + bf2f((u16)(vl & 0xffffu));
  float o = bf2f((u16)(vh >> 16))     + bf2f((u16)(vl >> 16));
  float re = e * cs - o * sn;
  float ro = e * sn + o * cs;
  u16 reh = f2bf(re), roh = f2bf(ro);
  u16 rel = f2bf(re - bf2f(reh)), rol = f2bf(ro - bf2f(roh));
  *(uint32_t*)(bh + off) = (uint32_t)reh | ((uint32_t)roh << 16);
  *(uint32_t*)(bl + off) = (uint32_t)rel | ((uint32_t)rol << 16);
}

// ---------------- split-precision GEMM: C = A @ B^T ----------------
struct GemmPtrs {
  const u16* Bh[3]; const u16* Bl[3];
  u16* C0[3]; u16* C1[3];
  int nt[3]; int mode[3];
};

__global__ __launch_bounds__(256) void gemm_bt_kernel(
    const u16* __restrict__ Ah, const u16* __restrict__ Al,
    GemmPtrs P, float* __restrict__ CF,
    int M, int N, int K, int out_f32)
{
  __shared__ __align__(16) u16 sAh[128 * 32];
  __shared__ __align__(16) u16 sAl[128 * 32];
  __shared__ __align__(16) u16 sBh[128 * 32];
  __shared__ __align__(16) u16 sBl[128 * 32];
  const int t = threadIdx.x, lane = t & 63;
  const int wave = t >> 6;
  const int g = lane >> 4, cl = lane & 15;
  const int z = blockIdx.z;
  const u16* Bh = P.Bh[z];
  const u16* Bl = P.Bl[z];
  const int nt = P.nt[z];
  const int n0 = blockIdx.x * 128, m0 = blockIdx.y * 128;
  const int wr = wave >> 1, wc = wave & 1;

  int srow[2], scol[2], soff[2];
#pragma unroll
  for (int j = 0; j < 2; ++j) {
    int c = j * 256 + t;
    srow[j] = c >> 2;
    scol[j] = ((c & 3) ^ (srow[j] & 3)) * 8;
    soff[j] = c * 16;
  }

  f32x4 acc[4][4] = {};

  for (int k0 = 0; k0 < K; k0 += 32) {
#pragma unroll
    for (int j = 0; j < 2; ++j) {
      gload_lds16(Ah + (size_t)(m0 + srow[j]) * K + k0 + scol[j], (uintptr_t)sAh + soff[j]);
      gload_lds16(Bh + (size_t)(n0 + srow[j]) * K + k0 + scol[j], (uintptr_t)sBh + soff[j]);
    }
    if (nt == 3) {
#pragma unroll
      for (int j = 0; j < 2; ++j) {
        gload_lds16(Al + (size_t)(m0 + srow[j]) * K + k0 + scol[j], (uintptr_t)sAl + soff[j]);
        gload_lds16(Bl + (size_t)(n0 + srow[j]) * K + k0 + scol[j], (uintptr_t)sBl + soff[j]);
      }
    }
    __syncthreads();

    bf16x8 afh[4], bfh[4];
#pragma unroll
    for (int m = 0; m < 4; ++m) {
      int row = wr * 64 + m * 16 + cl;
      afh[m] = *(const bf16x8*)&sAh[row * 32 + ((g ^ (row & 3)) * 8)];
    }
#pragma unroll
    for (int n = 0; n < 4; ++n) {
      int row = wc * 64 + n * 16 + cl;
      bfh[n] = *(const bf16x8*)&sBh[row * 32 + ((g ^ (row & 3)) * 8)];
    }
#pragma unroll
    for (int m = 0; m < 4; ++m)
#pragma unroll
      for (int n = 0; n < 4; ++n)
        acc[m][n] = MFMA16(afh[m], bfh[n], acc[m][n]);

    if (nt == 3) {
#pragma unroll
      for (int n = 0; n < 4; ++n) {
        int row = wc * 64 + n * 16 + cl;
        bf16x8 bfl = *(const bf16x8*)&sBl[row * 32 + ((g ^ (row & 3)) * 8)];
#pragma unroll
        for (int m = 0; m < 4; ++m)
          acc[m][n] = MFMA16(afh[m], bfl, acc[m][n]);
      }
#pragma unroll
      for (int m = 0; m < 4; ++m) {
        int row = wr * 64 + m * 16 + cl;
        bf16x8 afl = *(const bf16x8*)&sAl[row * 32 + ((g ^ (row & 3)) * 8)];
#pragma unroll
        for (int n = 0; n < 4; ++n)
          acc[m][n] = MFMA16(afl, bfh[n], acc[m][n]);
      }
    }
    __syncthreads();
  }

  if (out_f32) {
#pragma unroll
    for (int m = 0; m < 4; ++m)
#pragma unroll
      for (int n = 0; n < 4; ++n)
#pragma unroll
        for (int r = 0; r < 4; ++r) {
          int row = m0 + wr * 64 + m * 16 + g * 4 + r;
          int col = n0 + wc * 64 + n * 16 + cl;
          CF[(size_t)row * N + col] = acc[m][n][r];
        }
  } else if (P.mode[z] == 1) {
    u16* VT = P.C0[z];
#pragma unroll
    for (int m = 0; m < 4; ++m)
#pragma unroll
      for (int n = 0; n < 4; ++n) {
        int row0 = m0 + wr * 64 + m * 16 + g * 4;
        int col = n0 + wc * 64 + n * 16 + cl;
        union { u16 u[4]; uint2 v; } pk;
#pragma unroll
        for (int r = 0; r < 4; ++r) pk.u[r] = f2bf(acc[m][n][r]);
        *(uint2*)&VT[(size_t)col * M + row0] = pk.v;
      }
  } else {
    u16* Ch = P.C0[z];
    u16* Cl = P.C1[z];
#pragma unroll
    for (int m = 0; m < 4; ++m)
#pragma unroll
      for (int n = 0; n < 4; ++n)
#pragma unroll
        for (int r = 0; r < 4; ++r) {
          int row = m0 + wr * 64 + m * 16 + g * 4 + r;
          int col = n0 + wc * 64 + n * 16 + cl;
          float v = acc[m][n][r];
          u16 h = f2bf(v);
          Ch[(size_t)row * N + col] = h;
          Cl[(size_t)row * N + col] = f2bf(v - bf2f(h));
        }
  }
}

// ---------------- flash attention, causal, no K/V staging, no barriers ----------------
// grid (NH*NB, 8): x = (b,h) pair, y -> q-tile qi = 7 - y (heavy blocks dispatch first).
// 256 threads = 4 waves, each wave owns 32 q rows. LDS = 18 KB (P only, wave-private).
// __launch_bounds__(256,4): VGPR<=128 -> 4 blocks/CU = 16 waves/CU for latency hiding.
// K/V fragments read directly from global (L2-resident: 384 KB per (b,h)).
__global__ __launch_bounds__(256, 4) void attn_kernel(
    const u16* __restrict__ Qh, const u16* __restrict__ Ql,
    const u16* __restrict__ Kh, const u16* __restrict__ Kl,
    const u16* __restrict__ Vt,
    u16* __restrict__ Oh, u16* __restrict__ Ol)
{
  __shared__ __align__(16) u16 sP[128 * 72];   // 4 waves x 32 rows, stride 72

  const int t = threadIdx.x, lane = t & 63, wave = t >> 6;
  const int g = lane >> 4, cl = lane & 15;
  const int h = blockIdx.x & (NH - 1), b = blockIdx.x >> 4;
  const int qi = 7 - blockIdx.y;               // heavy-first
  const int q0 = qi * QBLK;
  const size_t rowbase = (size_t)b * SEQ;
  const int colbase = h * DH;
  const int MT = NB * SEQ;

  const u16* Khb = Kh + rowbase * DMODEL + colbase;
  const u16* Klb = Kl + rowbase * DMODEL + colbase;
  const u16* Vtb = Vt + (size_t)(h * DH) * MT + b * SEQ;

  // Q fragments (A-op: lane holds A[row=cl][k=g*8+e], second mfma k+32)
  bf16x8 qfh[2][2], qfl[2][2];
#pragma unroll
  for (int mf = 0; mf < 2; ++mf) {
    int qrow = q0 + wave * 32 + mf * 16 + cl;
    const u16* ph = Qh + (rowbase + qrow) * DMODEL + colbase + g * 8;
    const u16* pl = Ql + (rowbase + qrow) * DMODEL + colbase + g * 8;
    qfh[mf][0] = *(const bf16x8*)ph; qfh[mf][1] = *(const bf16x8*)(ph + 32);
    qfl[mf][0] = *(const bf16x8*)pl; qfl[mf][1] = *(const bf16x8*)(pl + 32);
  }

  bf16x8 ones;
#pragma unroll
  for (int e = 0; e < 8; ++e) ones[e] = (__bf16)1.0f;

  float m_run[2][4];
  f32x4 o_acc[2][4] = {};
  f32x4 o_l[2] = {};
#pragma unroll
  for (int mf = 0; mf < 2; ++mf)
#pragma unroll
    for (int r = 0; r < 4; ++r) m_run[mf][r] = -INFINITY;

  const int last = 2 * qi + 1;
  const int wrow0 = q0 + wave * 32;
  const int prow0 = wave * 32;

  for (int kt = 0; kt <= last; ++kt) {
    const int kv0 = kt * KVB;
    if (wrow0 + 31 < kv0) continue;          // fully masked for this wave
    const bool needmask = (kv0 + 63) > wrow0;

    // QK^T: 3-term split precision, K frags straight from global (L2)
    f32x4 s[2][4];
    __builtin_amdgcn_s_setprio(1);
#pragma unroll
    for (int n = 0; n < 4; ++n) {
      const u16* kp  = Khb + (size_t)(kv0 + n * 16 + cl) * DMODEL + g * 8;
      const u16* kpl = Klb + (size_t)(kv0 + n * 16 + cl) * DMODEL + g * 8;
      bf16x8 kh0 = *(const bf16x8*)kp;
      bf16x8 kh1 = *(const bf16x8*)(kp + 32);
      bf16x8 kl0 = *(const bf16x8*)kpl;
      bf16x8 kl1 = *(const bf16x8*)(kpl + 32);
#pragma unroll
      for (int mf = 0; mf < 2; ++mf) {
        f32x4 zz = {};
        zz = MFMA16(qfh[mf][0], kh0, zz);
        zz = MFMA16(qfh[mf][1], kh1, zz);
        zz = MFMA16(qfh[mf][0], kl0, zz);
        zz = MFMA16(qfh[mf][1], kl1, zz);
        zz = MFMA16(qfl[mf][0], kh0, zz);
        zz = MFMA16(qfl[mf][1], kh1, zz);
        s[mf][n] = zz;
      }
    }
    __builtin_amdgcn_s_setprio(0);

    // online softmax (max via 4 shfl; sum via ones-column MFMA below)
#pragma unroll
    for (int mf = 0; mf < 2; ++mf) {
#pragma unroll
      for (int r = 0; r < 4; ++r) {
        int qg = wrow0 + mf * 16 + g * 4 + r;
        float sv[4];
        float mx = -INFINITY;
#pragma unroll
        for (int n = 0; n < 4; ++n) {
          float x = s[mf][n][r];
          if (needmask && (kv0 + n * 16 + cl > qg)) x = -INFINITY;
          sv[n] = x;
          mx = fmaxf(mx, x);
        }
        mx = fmaxf(mx, __shfl_xor(mx, 1));
        mx = fmaxf(mx, __shfl_xor(mx, 2));
        mx = fmaxf(mx, __shfl_xor(mx, 4));
        mx = fmaxf(mx, __shfl_xor(mx, 8));
        float mold = m_run[mf][r];
        float mnew = fmaxf(mold, mx);
        float scale = exp2f((mold - mnew) * LOG2E);
        m_run[mf][r] = mnew;
        float mc = mnew * LOG2E;
        int prow = prow0 + mf * 16 + g * 4 + r;
#pragma unroll
        for (int n = 0; n < 4; ++n) {
          float p = exp2f(fmaf(sv[n], LOG2E, -mc));
          sP[prow * 72 + n * 16 + cl] = f2bf(p);
        }
        o_l[mf][r] *= scale;
#pragma unroll
        for (int n = 0; n < 4; ++n) o_acc[mf][n][r] *= scale;
      }
    }

    // PV: O += P(32x64)*Vt ; l += P*1 (ones column, rescaled identically)
    __builtin_amdgcn_s_setprio(1);
#pragma unroll
    for (int kk = 0; kk < 2; ++kk) {
      bf16x8 pa0 = *(const bf16x8*)&sP[(prow0 + cl) * 72 + kk * 32 + g * 8];
      bf16x8 pa1 = *(const bf16x8*)&sP[(prow0 + 16 + cl) * 72 + kk * 32 + g * 8];
#pragma unroll
      for (int n = 0; n < 4; ++n) {
        bf16x8 vf = *(const bf16x8*)(Vtb + (size_t)(n * 16 + cl) * MT + kv0 + kk * 32 + g * 8);
        o_acc[0][n] = MFMA16(pa0, vf, o_acc[0][n]);
        o_acc[1][n] = MFMA16(pa1, vf, o_acc[1][n]);
      }
      o_l[0] = MFMA16(pa0, ones, o_l[0]);
      o_l[1] = MFMA16(pa1, ones, o_l[1]);
    }
    __builtin_amdgcn_s_setprio(0);
  }

  // epilogue: normalize by in-register l, split hi/lo, store
#pragma unroll
  for (int mf = 0; mf < 2; ++mf)
#pragma unroll
    for (int n = 0; n < 4; ++n)
#pragma unroll
      for (int r = 0; r < 4; ++r) {
        float ov = o_acc[mf][n][r] / o_l[mf][r];
        int qrow = q0 + wave * 32 + mf * 16 + g * 4 + r;
        size_t idx = (rowbase + qrow) * DMODEL + colbase + n * 16 + cl;
        u16 hh = f2bf(ov);
        Oh[idx] = hh;
        Ol[idx] = f2bf(ov - bf2f(hh));
      }
}

extern "C" void kernel_launch(void* const* d_in, const int* in_sizes, int n_in,
                              void* d_out, int out_size, void* d_ws, size_t ws_size,
                              hipStream_t stream) {
  const float* x  = (const float*)d_in[0];
  const float* Wq = (const float*)d_in[1];
  const float* Wk = (const float*)d_in[2];
  const float* Wv = (const float*)d_in[3];
  const float* Wo = (const float*)d_in[4];
  float* out = (float*)d_out;

  const int M = NB * SEQ;      // 4096
  const int D = DMODEL;        // 1024
  char* ws = (char*)d_ws;
  const size_t MB = 1u << 20;
  u16* xh  = (u16*)(ws + 0 * MB);
  u16* xl  = (u16*)(ws + 8 * MB);
  u16* qh  = (u16*)(ws + 16 * MB);
  u16* ql  = (u16*)(ws + 24 * MB);
  u16* kh  = (u16*)(ws + 32 * MB);
  u16* kl  = (u16*)(ws + 40 * MB);
  u16* vt  = (u16*)(ws + 48 * MB);   // V transposed: [1024 cols][4096 tokens]
  u16* wqh = (u16*)(ws + 56 * MB);
  u16* wql = (u16*)(ws + 58 * MB);
  u16* wkh = (u16*)(ws + 60 * MB);
  u16* wkl = (u16*)(ws + 62 * MB);
  u16* wvh = (u16*)(ws + 64 * MB);
  u16* wvl = (u16*)(ws + 66 * MB);
  u16* woh = (u16*)(ws + 68 * MB);
  u16* wol = (u16*)(ws + 70 * MB);
  u16* oh  = xh;   // x dead after QKV GEMM
  u16* ol  = xl;

  // splits
  split_kernel<<<(M * D / 8 + 255) / 256, 256, 0, stream>>>(x, xh, xl, M * D / 8);
  split_kernel<<<(D * D / 8 + 255) / 256, 256, 0, stream>>>(Wq, wqh, wql, D * D / 8);
  split_kernel<<<(D * D / 8 + 255) / 256, 256, 0, stream>>>(Wk, wkh, wkl, D * D / 8);
  split_kernel<<<(D * D / 8 + 255) / 256, 256, 0, stream>>>(Wv, wvh, wvl, D * D / 8);
  split_kernel<<<(D * D / 8 + 255) / 256, 256, 0, stream>>>(Wo, woh, wol, D * D / 8);

  // fused QKV projections: Q,K 3-term hi/lo out; V 1-term transposed out
  {
    GemmPtrs P;
    P.Bh[0] = wqh; P.Bh[1] = wkh; P.Bh[2] = wvh;
    P.Bl[0] = wql; P.Bl[1] = wkl; P.Bl[2] = wvl;
    P.C0[0] = qh;  P.C0[1] = kh;  P.C0[2] = vt;
    P.C1[0] = ql;  P.C1[1] = kl;  P.C1[2] = nullptr;
    P.nt[0] = 3;   P.nt[1] = 3;   P.nt[2] = 1;
    P.mode[0] = 0; P.mode[1] = 0; P.mode[2] = 1;
    gemm_bt_kernel<<<dim3(D / 128, M / 128, 3), 256, 0, stream>>>(
        xh, xl, P, nullptr, M, D, D, 0);
  }

  // RoPE on Q,K (hi/lo, in place)
  rope_kernel<<<(2 * M * (D / 2) + 255) / 256, 256, 0, stream>>>(qh, ql, kh, kl);

  // causal flash attention: 512 blocks of 4 waves, heavy tiles first
  attn_kernel<<<dim3(NH * NB, 8), 256, 0, stream>>>(qh, ql, kh, kl, vt, oh, ol);

  // output projection, 3-term, f32 out
  {
    GemmPtrs P;
    P.Bh[0] = woh; P.Bh[1] = woh; P.Bh[2] = woh;
    P.Bl[0] = wol; P.Bl[1] = wol; P.Bl[2] = wol;
    P.C0[0] = nullptr; P.C0[1] = nullptr; P.C0[2] = nullptr;
    P.C1[0] = nullptr; P.C1[1] = nullptr; P.C1[2] = nullptr;
    P.nt[0] = 3;   P.nt[1] = 3;   P.nt[2] = 3;
    P.mode[0] = 0; P.mode[1] = 0; P.mode[2] = 0;
    gemm_bt_kernel<<<dim3(D / 128, M / 128, 1), 256, 0, stream>>>(
        oh, ol, P, out, M, D, D, 1);
  }
}

// Round 6
// 228.084 us; speedup vs baseline: 1.1919x; 1.1919x over previous
//
#include <hip/hip_runtime.h>
#include <stdint.h>

typedef unsigned short u16;
typedef __bf16 bf16x8 __attribute__((ext_vector_type(8)));
typedef float f32x4 __attribute__((ext_vector_type(4)));

#define SEQ    1024
#define DMODEL 1024
#define NB     4
#define NH     16
#define DH     64
#define QBLK   128
#define KVB    64
#define LOG2E  1.4426950408889634f

// ---------- bf16 helpers ----------
__device__ __forceinline__ u16 f2bf(float f) {
  uint32_t u = __builtin_bit_cast(uint32_t, f);
  u += 0x7fffu + ((u >> 16) & 1u);   // round-to-nearest-even
  return (u16)(u >> 16);
}
__device__ __forceinline__ float bf2f(u16 h) {
  uint32_t u = ((uint32_t)h) << 16;
  return __builtin_bit_cast(float, u);
}

#define MFMA16(a, b, c) __builtin_amdgcn_mfma_f32_16x16x32_bf16((a), (b), (c), 0, 0, 0)

// ---------- async global->LDS (16B) ----------
__device__ __forceinline__ void gload_lds16(const u16* g, uintptr_t lds_addr) {
  __builtin_amdgcn_global_load_lds(
      (__attribute__((address_space(1))) void*)(uintptr_t)g,
      (__attribute__((address_space(3))) void*)lds_addr,
      16, 0, 0);
}

// ---------------- split f32 -> (hi, lo) bf16, 8 elems / thread ----------------
__global__ void split_kernel(const float* __restrict__ src, u16* __restrict__ hi,
                             u16* __restrict__ lo, int n8) {
  int i = blockIdx.x * blockDim.x + threadIdx.x;
  if (i >= n8) return;
  float f[8];
  float4 v0 = *(const float4*)(src + (size_t)i * 8);
  float4 v1 = *(const float4*)(src + (size_t)i * 8 + 4);
  f[0] = v0.x; f[1] = v0.y; f[2] = v0.z; f[3] = v0.w;
  f[4] = v1.x; f[5] = v1.y; f[6] = v1.z; f[7] = v1.w;
  union { u16 u[8]; uint4 v; } H, L;
#pragma unroll
  for (int e = 0; e < 8; ++e) {
    u16 h = f2bf(f[e]);
    H.u[e] = h;
    L.u[e] = f2bf(f[e] - bf2f(h));
  }
  *(uint4*)(hi + (size_t)i * 8) = H.v;
  *(uint4*)(lo + (size_t)i * 8) = L.v;
}

// ---------------- RoPE on Q,K hi/lo pairs (in place) ----------------
__global__ void rope_kernel(u16* __restrict__ Qh, u16* __restrict__ Ql,
                            u16* __restrict__ Kh, u16* __restrict__ Kl) {
  const int nP = (NB * SEQ) * (DMODEL / 2);
  int idx = blockIdx.x * blockDim.x + threadIdx.x;
  u16 *bh, *bl; int p;
  if (idx < nP) { bh = Qh; bl = Ql; p = idx; }
  else          { bh = Kh; bl = Kl; p = idx - nP; }
  int row = p >> 9;           // 512 pairs per row
  int pi  = p & 511;
  int t   = row & (SEQ - 1);
  int fi  = pi & 31;
  float inv = exp2f((float)fi * (-13.287712379549449f / 32.0f)); // 10000^(-fi/32)
  float ang = (float)t * inv;
  float sn, cs;
  sincosf(ang, &sn, &cs);
  size_t off = (size_t)row * DMODEL + pi * 2;
  uint32_t vh = *(uint32_t*)(bh + off);
  uint32_t vl = *(uint32_t*)(bl + off);
  float e = bf2f((u16)(vh & 0xffffu)) + bf2f((u16)(vl & 0xffffu));
  float o = bf2f((u16)(vh >> 16))     + bf2f((u16)(vl >> 16));
  float re = e * cs - o * sn;
  float ro = e * sn + o * cs;
  u16 reh = f2bf(re), roh = f2bf(ro);
  u16 rel = f2bf(re - bf2f(reh)), rol = f2bf(ro - bf2f(roh));
  *(uint32_t*)(bh + off) = (uint32_t)reh | ((uint32_t)roh << 16);
  *(uint32_t*)(bl + off) = (uint32_t)rel | ((uint32_t)rol << 16);
}

// ---------------- split-precision GEMM: C = A @ B^T ----------------
struct GemmPtrs {
  const u16* Bh[3]; const u16* Bl[3];
  u16* C0[3]; u16* C1[3];
  int nt[3]; int mode[3];
};

__global__ __launch_bounds__(256) void gemm_bt_kernel(
    const u16* __restrict__ Ah, const u16* __restrict__ Al,
    GemmPtrs P, float* __restrict__ CF,
    int M, int N, int K, int out_f32)
{
  __shared__ __align__(16) u16 sAh[128 * 32];
  __shared__ __align__(16) u16 sAl[128 * 32];
  __shared__ __align__(16) u16 sBh[128 * 32];
  __shared__ __align__(16) u16 sBl[128 * 32];
  const int t = threadIdx.x, lane = t & 63;
  const int wave = t >> 6;
  const int g = lane >> 4, cl = lane & 15;
  const int z = blockIdx.z;
  const u16* Bh = P.Bh[z];
  const u16* Bl = P.Bl[z];
  const int nt = P.nt[z];
  const int n0 = blockIdx.x * 128, m0 = blockIdx.y * 128;
  const int wr = wave >> 1, wc = wave & 1;

  int srow[2], scol[2], soff[2];
#pragma unroll
  for (int j = 0; j < 2; ++j) {
    int c = j * 256 + t;
    srow[j] = c >> 2;
    scol[j] = ((c & 3) ^ (srow[j] & 3)) * 8;
    soff[j] = c * 16;
  }

  f32x4 acc[4][4] = {};

  for (int k0 = 0; k0 < K; k0 += 32) {
#pragma unroll
    for (int j = 0; j < 2; ++j) {
      gload_lds16(Ah + (size_t)(m0 + srow[j]) * K + k0 + scol[j], (uintptr_t)sAh + soff[j]);
      gload_lds16(Bh + (size_t)(n0 + srow[j]) * K + k0 + scol[j], (uintptr_t)sBh + soff[j]);
    }
    if (nt == 3) {
#pragma unroll
      for (int j = 0; j < 2; ++j) {
        gload_lds16(Al + (size_t)(m0 + srow[j]) * K + k0 + scol[j], (uintptr_t)sAl + soff[j]);
        gload_lds16(Bl + (size_t)(n0 + srow[j]) * K + k0 + scol[j], (uintptr_t)sBl + soff[j]);
      }
    }
    __syncthreads();

    bf16x8 afh[4], bfh[4];
#pragma unroll
    for (int m = 0; m < 4; ++m) {
      int row = wr * 64 + m * 16 + cl;
      afh[m] = *(const bf16x8*)&sAh[row * 32 + ((g ^ (row & 3)) * 8)];
    }
#pragma unroll
    for (int n = 0; n < 4; ++n) {
      int row = wc * 64 + n * 16 + cl;
      bfh[n] = *(const bf16x8*)&sBh[row * 32 + ((g ^ (row & 3)) * 8)];
    }
#pragma unroll
    for (int m = 0; m < 4; ++m)
#pragma unroll
      for (int n = 0; n < 4; ++n)
        acc[m][n] = MFMA16(afh[m], bfh[n], acc[m][n]);

    if (nt == 3) {
#pragma unroll
      for (int n = 0; n < 4; ++n) {
        int row = wc * 64 + n * 16 + cl;
        bf16x8 bfl = *(const bf16x8*)&sBl[row * 32 + ((g ^ (row & 3)) * 8)];
#pragma unroll
        for (int m = 0; m < 4; ++m)
          acc[m][n] = MFMA16(afh[m], bfl, acc[m][n]);
      }
#pragma unroll
      for (int m = 0; m < 4; ++m) {
        int row = wr * 64 + m * 16 + cl;
        bf16x8 afl = *(const bf16x8*)&sAl[row * 32 + ((g ^ (row & 3)) * 8)];
#pragma unroll
        for (int n = 0; n < 4; ++n)
          acc[m][n] = MFMA16(afl, bfh[n], acc[m][n]);
      }
    }
    __syncthreads();
  }

  if (out_f32) {
#pragma unroll
    for (int m = 0; m < 4; ++m)
#pragma unroll
      for (int n = 0; n < 4; ++n)
#pragma unroll
        for (int r = 0; r < 4; ++r) {
          int row = m0 + wr * 64 + m * 16 + g * 4 + r;
          int col = n0 + wc * 64 + n * 16 + cl;
          CF[(size_t)row * N + col] = acc[m][n][r];
        }
  } else if (P.mode[z] == 1) {
    u16* VT = P.C0[z];
#pragma unroll
    for (int m = 0; m < 4; ++m)
#pragma unroll
      for (int n = 0; n < 4; ++n) {
        int row0 = m0 + wr * 64 + m * 16 + g * 4;
        int col = n0 + wc * 64 + n * 16 + cl;
        union { u16 u[4]; uint2 v; } pk;
#pragma unroll
        for (int r = 0; r < 4; ++r) pk.u[r] = f2bf(acc[m][n][r]);
        *(uint2*)&VT[(size_t)col * M + row0] = pk.v;
      }
  } else {
    u16* Ch = P.C0[z];
    u16* Cl = P.C1[z];
#pragma unroll
    for (int m = 0; m < 4; ++m)
#pragma unroll
      for (int n = 0; n < 4; ++n)
#pragma unroll
        for (int r = 0; r < 4; ++r) {
          int row = m0 + wr * 64 + m * 16 + g * 4 + r;
          int col = n0 + wc * 64 + n * 16 + cl;
          float v = acc[m][n][r];
          u16 h = f2bf(v);
          Ch[(size_t)row * N + col] = h;
          Cl[(size_t)row * N + col] = f2bf(v - bf2f(h));
        }
  }
}

// ---------------- flash attention, causal, no K/V staging, no barriers ----------------
// grid (NH*NB, 8): x = (b,h) pair, y -> q-tile qi = 7 - y (heavy blocks dispatch first).
// 256 threads = 4 waves, each wave owns 32 q rows. LDS = 18 KB (P only, wave-private).
// __launch_bounds__(256,2): VGPR cap 256 -> NO SPILLS (R5's (256,4) forced 64 VGPR +
// 76 MB scratch traffic). Compiler lands ~90-130 regs -> 2-3 blocks/CU resident.
__global__ __launch_bounds__(256, 2) void attn_kernel(
    const u16* __restrict__ Qh, const u16* __restrict__ Ql,
    const u16* __restrict__ Kh, const u16* __restrict__ Kl,
    const u16* __restrict__ Vt,
    u16* __restrict__ Oh, u16* __restrict__ Ol)
{
  __shared__ __align__(16) u16 sP[128 * 72];   // 4 waves x 32 rows, stride 72

  const int t = threadIdx.x, lane = t & 63, wave = t >> 6;
  const int g = lane >> 4, cl = lane & 15;
  const int h = blockIdx.x & (NH - 1), b = blockIdx.x >> 4;
  const int qi = 7 - blockIdx.y;               // heavy-first
  const int q0 = qi * QBLK;
  const size_t rowbase = (size_t)b * SEQ;
  const int colbase = h * DH;
  const int MT = NB * SEQ;

  const u16* Khb = Kh + rowbase * DMODEL + colbase;
  const u16* Klb = Kl + rowbase * DMODEL + colbase;
  const u16* Vtb = Vt + (size_t)(h * DH) * MT + b * SEQ;

  // Q fragments (A-op: lane holds A[row=cl][k=g*8+e], second mfma k+32)
  bf16x8 qfh[2][2], qfl[2][2];
#pragma unroll
  for (int mf = 0; mf < 2; ++mf) {
    int qrow = q0 + wave * 32 + mf * 16 + cl;
    const u16* ph = Qh + (rowbase + qrow) * DMODEL + colbase + g * 8;
    const u16* pl = Ql + (rowbase + qrow) * DMODEL + colbase + g * 8;
    qfh[mf][0] = *(const bf16x8*)ph; qfh[mf][1] = *(const bf16x8*)(ph + 32);
    qfl[mf][0] = *(const bf16x8*)pl; qfl[mf][1] = *(const bf16x8*)(pl + 32);
  }

  bf16x8 ones;
#pragma unroll
  for (int e = 0; e < 8; ++e) ones[e] = (__bf16)1.0f;

  float m_run[2][4];
  f32x4 o_acc[2][4] = {};
  f32x4 o_l[2] = {};
#pragma unroll
  for (int mf = 0; mf < 2; ++mf)
#pragma unroll
    for (int r = 0; r < 4; ++r) m_run[mf][r] = -INFINITY;

  const int last = 2 * qi + 1;
  const int wrow0 = q0 + wave * 32;
  const int prow0 = wave * 32;

  for (int kt = 0; kt <= last; ++kt) {
    const int kv0 = kt * KVB;
    if (wrow0 + 31 < kv0) continue;          // fully masked for this wave
    const bool needmask = (kv0 + 63) > wrow0;

    // QK^T: 3-term split precision, K frags straight from global (L2)
    f32x4 s[2][4];
    __builtin_amdgcn_s_setprio(1);
#pragma unroll
    for (int n = 0; n < 4; ++n) {
      const u16* kp  = Khb + (size_t)(kv0 + n * 16 + cl) * DMODEL + g * 8;
      const u16* kpl = Klb + (size_t)(kv0 + n * 16 + cl) * DMODEL + g * 8;
      bf16x8 kh0 = *(const bf16x8*)kp;
      bf16x8 kh1 = *(const bf16x8*)(kp + 32);
      bf16x8 kl0 = *(const bf16x8*)kpl;
      bf16x8 kl1 = *(const bf16x8*)(kpl + 32);
#pragma unroll
      for (int mf = 0; mf < 2; ++mf) {
        f32x4 zz = {};
        zz = MFMA16(qfh[mf][0], kh0, zz);
        zz = MFMA16(qfh[mf][1], kh1, zz);
        zz = MFMA16(qfh[mf][0], kl0, zz);
        zz = MFMA16(qfh[mf][1], kl1, zz);
        zz = MFMA16(qfl[mf][0], kh0, zz);
        zz = MFMA16(qfl[mf][1], kh1, zz);
        s[mf][n] = zz;
      }
    }
    __builtin_amdgcn_s_setprio(0);

    // online softmax (max via 4 shfl; sum via ones-column MFMA below)
#pragma unroll
    for (int mf = 0; mf < 2; ++mf) {
#pragma unroll
      for (int r = 0; r < 4; ++r) {
        int qg = wrow0 + mf * 16 + g * 4 + r;
        float sv[4];
        float mx = -INFINITY;
#pragma unroll
        for (int n = 0; n < 4; ++n) {
          float x = s[mf][n][r];
          if (needmask && (kv0 + n * 16 + cl > qg)) x = -INFINITY;
          sv[n] = x;
          mx = fmaxf(mx, x);
        }
        mx = fmaxf(mx, __shfl_xor(mx, 1));
        mx = fmaxf(mx, __shfl_xor(mx, 2));
        mx = fmaxf(mx, __shfl_xor(mx, 4));
        mx = fmaxf(mx, __shfl_xor(mx, 8));
        float mold = m_run[mf][r];
        float mnew = fmaxf(mold, mx);
        float scale = exp2f((mold - mnew) * LOG2E);
        m_run[mf][r] = mnew;
        float mc = mnew * LOG2E;
        int prow = prow0 + mf * 16 + g * 4 + r;
#pragma unroll
        for (int n = 0; n < 4; ++n) {
          float p = exp2f(fmaf(sv[n], LOG2E, -mc));
          sP[prow * 72 + n * 16 + cl] = f2bf(p);
        }
        o_l[mf][r] *= scale;
#pragma unroll
        for (int n = 0; n < 4; ++n) o_acc[mf][n][r] *= scale;
      }
    }

    // PV: O += P(32x64)*Vt ; l += P*1 (ones column, rescaled identically)
    __builtin_amdgcn_s_setprio(1);
#pragma unroll
    for (int kk = 0; kk < 2; ++kk) {
      bf16x8 pa0 = *(const bf16x8*)&sP[(prow0 + cl) * 72 + kk * 32 + g * 8];
      bf16x8 pa1 = *(const bf16x8*)&sP[(prow0 + 16 + cl) * 72 + kk * 32 + g * 8];
#pragma unroll
      for (int n = 0; n < 4; ++n) {
        bf16x8 vf = *(const bf16x8*)(Vtb + (size_t)(n * 16 + cl) * MT + kv0 + kk * 32 + g * 8);
        o_acc[0][n] = MFMA16(pa0, vf, o_acc[0][n]);
        o_acc[1][n] = MFMA16(pa1, vf, o_acc[1][n]);
      }
      o_l[0] = MFMA16(pa0, ones, o_l[0]);
      o_l[1] = MFMA16(pa1, ones, o_l[1]);
    }
    __builtin_amdgcn_s_setprio(0);
  }

  // epilogue: normalize by in-register l, split hi/lo, store
#pragma unroll
  for (int mf = 0; mf < 2; ++mf)
#pragma unroll
    for (int n = 0; n < 4; ++n)
#pragma unroll
      for (int r = 0; r < 4; ++r) {
        float ov = o_acc[mf][n][r] / o_l[mf][r];
        int qrow = q0 + wave * 32 + mf * 16 + g * 4 + r;
        size_t idx = (rowbase + qrow) * DMODEL + colbase + n * 16 + cl;
        u16 hh = f2bf(ov);
        Oh[idx] = hh;
        Ol[idx] = f2bf(ov - bf2f(hh));
      }
}

extern "C" void kernel_launch(void* const* d_in, const int* in_sizes, int n_in,
                              void* d_out, int out_size, void* d_ws, size_t ws_size,
                              hipStream_t stream) {
  const float* x  = (const float*)d_in[0];
  const float* Wq = (const float*)d_in[1];
  const float* Wk = (const float*)d_in[2];
  const float* Wv = (const float*)d_in[3];
  const float* Wo = (const float*)d_in[4];
  float* out = (float*)d_out;

  const int M = NB * SEQ;      // 4096
  const int D = DMODEL;        // 1024
  char* ws = (char*)d_ws;
  const size_t MB = 1u << 20;
  u16* xh  = (u16*)(ws + 0 * MB);
  u16* xl  = (u16*)(ws + 8 * MB);
  u16* qh  = (u16*)(ws + 16 * MB);
  u16* ql  = (u16*)(ws + 24 * MB);
  u16* kh  = (u16*)(ws + 32 * MB);
  u16* kl  = (u16*)(ws + 40 * MB);
  u16* vt  = (u16*)(ws + 48 * MB);   // V transposed: [1024 cols][4096 tokens]
  u16* wqh = (u16*)(ws + 56 * MB);
  u16* wql = (u16*)(ws + 58 * MB);
  u16* wkh = (u16*)(ws + 60 * MB);
  u16* wkl = (u16*)(ws + 62 * MB);
  u16* wvh = (u16*)(ws + 64 * MB);
  u16* wvl = (u16*)(ws + 66 * MB);
  u16* woh = (u16*)(ws + 68 * MB);
  u16* wol = (u16*)(ws + 70 * MB);
  u16* oh  = xh;   // x dead after QKV GEMM
  u16* ol  = xl;

  // splits
  split_kernel<<<(M * D / 8 + 255) / 256, 256, 0, stream>>>(x, xh, xl, M * D / 8);
  split_kernel<<<(D * D / 8 + 255) / 256, 256, 0, stream>>>(Wq, wqh, wql, D * D / 8);
  split_kernel<<<(D * D / 8 + 255) / 256, 256, 0, stream>>>(Wk, wkh, wkl, D * D / 8);
  split_kernel<<<(D * D / 8 + 255) / 256, 256, 0, stream>>>(Wv, wvh, wvl, D * D / 8);
  split_kernel<<<(D * D / 8 + 255) / 256, 256, 0, stream>>>(Wo, woh, wol, D * D / 8);

  // fused QKV projections: Q,K 3-term hi/lo out; V 1-term transposed out
  {
    GemmPtrs P;
    P.Bh[0] = wqh; P.Bh[1] = wkh; P.Bh[2] = wvh;
    P.Bl[0] = wql; P.Bl[1] = wkl; P.Bl[2] = wvl;
    P.C0[0] = qh;  P.C0[1] = kh;  P.C0[2] = vt;
    P.C1[0] = ql;  P.C1[1] = kl;  P.C1[2] = nullptr;
    P.nt[0] = 3;   P.nt[1] = 3;   P.nt[2] = 1;
    P.mode[0] = 0; P.mode[1] = 0; P.mode[2] = 1;
    gemm_bt_kernel<<<dim3(D / 128, M / 128, 3), 256, 0, stream>>>(
        xh, xl, P, nullptr, M, D, D, 0);
  }

  // RoPE on Q,K (hi/lo, in place)
  rope_kernel<<<(2 * M * (D / 2) + 255) / 256, 256, 0, stream>>>(qh, ql, kh, kl);

  // causal flash attention: 512 blocks of 4 waves, heavy tiles first
  attn_kernel<<<dim3(NH * NB, 8), 256, 0, stream>>>(qh, ql, kh, kl, vt, oh, ol);

  // output projection, 3-term, f32 out
  {
    GemmPtrs P;
    P.Bh[0] = woh; P.Bh[1] = woh; P.Bh[2] = woh;
    P.Bl[0] = wol; P.Bl[1] = wol; P.Bl[2] = wol;
    P.C0[0] = nullptr; P.C0[1] = nullptr; P.C0[2] = nullptr;
    P.C1[0] = nullptr; P.C1[1] = nullptr; P.C1[2] = nullptr;
    P.nt[0] = 3;   P.nt[1] = 3;   P.nt[2] = 3;
    P.mode[0] = 0; P.mode[1] = 0; P.mode[2] = 0;
    gemm_bt_kernel<<<dim3(D / 128, M / 128, 1), 256, 0, stream>>>(
        oh, ol, P, out, M, D, D, 1);
  }
}